// Round 1
// baseline (1357.572 us; speedup 1.0000x reference)
//
#include <hip/hip_runtime.h>
#include <stdint.h>

#define S_LEN 2048
#define NB 4
#define NH 8

typedef __attribute__((ext_vector_type(8))) short s8v;
typedef __attribute__((ext_vector_type(4))) float f4v;

#define MFMA16(a, b, c) __builtin_amdgcn_mfma_f32_16x16x32_bf16((a), (b), (c), 0, 0, 0)

static __device__ __forceinline__ unsigned short f2bf(float f) {
    unsigned int u = __builtin_bit_cast(unsigned int, f);
    u += 0x7fffu + ((u >> 16) & 1u);
    return (unsigned short)(u >> 16);
}
static __device__ __forceinline__ float bf2f(unsigned short h) {
    unsigned int u = ((unsigned int)h) << 16;
    return __builtin_bit_cast(float, u);
}

// C[8192][512] = A[8192][512] @ W[512][512] + bias
// MODE 0: C bf16 row-major. MODE 1: C bf16 transposed per batch: C[b][n][s].
// MODE 2: C fp32 row-major.
template <int MODE, bool ABF16>
__global__ __launch_bounds__(256) void gemm_tile(
    const void* __restrict__ Av, const float* __restrict__ W,
    const float* __restrict__ bias, void* __restrict__ Cv)
{
    __shared__ unsigned short a_lds[64 * 32];
    __shared__ unsigned short wt_lds[64 * 32];
    const int t = threadIdx.x;
    const int w = t >> 6, lane = t & 63;
    const int quad = lane >> 4, l15 = lane & 15;
    const int m0 = blockIdx.x * 64, n0 = blockIdx.y * 64;

    f4v acc[4] = {};

    const int srow = t >> 2, sc8 = (t & 3) * 8;   // A staging: 64 rows x 32 k
    const int wkk = t >> 3, wnn = (t & 7) * 8;    // W staging: 32 k x 64 n

    for (int k0 = 0; k0 < 512; k0 += 32) {
        __syncthreads();
        if constexpr (ABF16) {
            const unsigned short* ap =
                (const unsigned short*)Av + (size_t)(m0 + srow) * 512 + k0 + sc8;
            *(uint4*)&a_lds[srow * 32 + sc8] = *(const uint4*)ap;
        } else {
            const float* ap = (const float*)Av + (size_t)(m0 + srow) * 512 + k0 + sc8;
            f4v v0 = *(const f4v*)ap;
            f4v v1 = *(const f4v*)(ap + 4);
            *(ushort4*)&a_lds[srow * 32 + sc8] =
                make_ushort4(f2bf(v0[0]), f2bf(v0[1]), f2bf(v0[2]), f2bf(v0[3]));
            *(ushort4*)&a_lds[srow * 32 + sc8 + 4] =
                make_ushort4(f2bf(v1[0]), f2bf(v1[1]), f2bf(v1[2]), f2bf(v1[3]));
        }
        {
            const float* wp = W + (size_t)(k0 + wkk) * 512 + n0 + wnn;
            f4v a0 = *(const f4v*)wp;
            f4v a1 = *(const f4v*)(wp + 4);
            #pragma unroll
            for (int i = 0; i < 4; ++i) wt_lds[(wnn + i) * 32 + wkk] = f2bf(a0[i]);
            #pragma unroll
            for (int i = 0; i < 4; ++i) wt_lds[(wnn + 4 + i) * 32 + wkk] = f2bf(a1[i]);
        }
        __syncthreads();
        s8v wf = *(const s8v*)&wt_lds[(w * 16 + l15) * 32 + quad * 8];
        #pragma unroll
        for (int rt = 0; rt < 4; ++rt) {
            s8v af = *(const s8v*)&a_lds[(rt * 16 + l15) * 32 + quad * 8];
            acc[rt] = MFMA16(af, wf, acc[rt]);
        }
    }

    const float bv = bias[n0 + w * 16 + l15];
    const int n = n0 + w * 16 + l15;
    #pragma unroll
    for (int rt = 0; rt < 4; ++rt) {
        const int mb = m0 + rt * 16 + quad * 4;
        if constexpr (MODE == 0) {
            unsigned short* C = (unsigned short*)Cv;
            #pragma unroll
            for (int r = 0; r < 4; ++r)
                C[(size_t)(mb + r) * 512 + n] = f2bf(acc[rt][r] + bv);
        } else if constexpr (MODE == 1) {
            unsigned short* C = (unsigned short*)Cv;
            ushort4 u = make_ushort4(f2bf(acc[rt][0] + bv), f2bf(acc[rt][1] + bv),
                                     f2bf(acc[rt][2] + bv), f2bf(acc[rt][3] + bv));
            *(ushort4*)&C[(size_t)(mb >> 11) * (512 * 2048) + (size_t)n * 2048 + (mb & 2047)] = u;
        } else {
            float* C = (float*)Cv;
            #pragma unroll
            for (int r = 0; r < 4; ++r)
                C[(size_t)(mb + r) * 512 + n] = acc[rt][r] + bv;
        }
    }
}

// x[8192][32] = qp_bf16[8192][512] @ wx[512][32] + bx
__global__ __launch_bounds__(256) void xproj_kernel(
    const unsigned short* __restrict__ qp, const float* __restrict__ wx,
    const float* __restrict__ bx, float* __restrict__ xout)
{
    __shared__ unsigned short qrow[8 * 512];
    const int t = threadIdx.x;
    const size_t base = (size_t)blockIdx.x * 8 * 512;
    #pragma unroll
    for (int i = 0; i < 2; ++i) {
        const int idx = (i * 256 + t) * 8;
        *(uint4*)&qrow[idx] = *(const uint4*)&qp[base + idx];
    }
    __syncthreads();
    const int r = t >> 5, j = t & 31;
    float acc = bx[j];
    #pragma unroll 8
    for (int d = 0; d < 512; ++d)
        acc = fmaf(bf2f(qrow[r * 512 + d]), wx[d * 32 + j], acc);
    xout[(size_t)blockIdx.x * 256 + t] = acc;
}

// Fused attention: logits = QK^T/8 + xdiff-bias/2, softmax (no max-sub; logits
// bounded ~|2|), writes normalized attn, accumulates PV -> obuf [b][s][h*64+d].
// One workgroup = (b, 16 q-rows); wave w handles heads 2w, 2w+1. Two passes:
// pass0 row-sums l (registers only), pass1 recompute + write + PV.
__global__ __launch_bounds__(256) void attn_kernel(
    const unsigned short* __restrict__ qp, const unsigned short* __restrict__ kp,
    const unsigned short* __restrict__ vT, const float* __restrict__ xws,
    const float* __restrict__ xdiff, float* __restrict__ attn,
    unsigned short* __restrict__ obuf)
{
    __shared__ float x_lds[16 * 32];
    __shared__ unsigned short p_lds[4 * 2 * 16 * 32];  // [wave][e][q16][k32], wave-private
    const int t = threadIdx.x, w = t >> 6, lane = t & 63;
    const int quad = lane >> 4, l15 = lane & 15;
    const int b = blockIdx.y, q0 = blockIdx.x * 16;
    const int h0 = 2 * w;

    {
        const float* src = xws + ((size_t)(b * S_LEN) + q0) * 32;
        x_lds[t] = src[t];
        x_lds[t + 256] = src[t + 256];
    }
    __syncthreads();

    // Q fragments (A-operand: row m=l15, k=quad*8+j), resident for whole kernel
    s8v qf[2][2];
    #pragma unroll
    for (int e = 0; e < 2; ++e)
        #pragma unroll
        for (int kk = 0; kk < 2; ++kk)
            qf[e][kk] = *(const s8v*)&qp[((size_t)(b * S_LEN + q0 + l15)) * 512 +
                                         (h0 + e) * 64 + kk * 32 + quad * 8];

    // x rows for this lane's 4 C-layout rows (bias einsum operand)
    f4v xh[2][4];
    #pragma unroll
    for (int e = 0; e < 2; ++e)
        #pragma unroll
        for (int r = 0; r < 4; ++r)
            xh[e][r] = *(const f4v*)&x_lds[(quad * 4 + r) * 32 + (h0 + e) * 4];

    const size_t kp_base = (size_t)b * S_LEN * 512;
    const size_t xd_base = ((size_t)(b * S_LEN) + q0) * S_LEN * 4;
    const size_t vt_base = (size_t)b * 512 * S_LEN;

    float lpart[2][4] = {};

    // ---- pass 0: row sums of exp(logits) ----
    for (int k0 = 0; k0 < S_LEN; k0 += 32) {
        s8v kf[2][2][2];
        #pragma unroll
        for (int e = 0; e < 2; ++e)
            #pragma unroll
            for (int kt = 0; kt < 2; ++kt)
                #pragma unroll
                for (int kk = 0; kk < 2; ++kk)
                    kf[e][kt][kk] = *(const s8v*)&kp[kp_base +
                        (size_t)(k0 + kt * 16 + l15) * 512 + (h0 + e) * 64 + kk * 32 + quad * 8];
        f4v xd[2][4];
        #pragma unroll
        for (int kt = 0; kt < 2; ++kt)
            #pragma unroll
            for (int r = 0; r < 4; ++r)
                xd[kt][r] = *(const f4v*)&xdiff[xd_base +
                    ((size_t)(quad * 4 + r) * S_LEN + k0 + kt * 16 + l15) * 4];

        #pragma unroll
        for (int e = 0; e < 2; ++e) {
            #pragma unroll
            for (int kt = 0; kt < 2; ++kt) {
                f4v c = {0.f, 0.f, 0.f, 0.f};
                c = MFMA16(qf[e][0], kf[e][kt][0], c);
                c = MFMA16(qf[e][1], kf[e][kt][1], c);
                #pragma unroll
                for (int r = 0; r < 4; ++r) {
                    float bias4 = xd[kt][r][0] * xh[e][r][0] + xd[kt][r][1] * xh[e][r][1] +
                                  xd[kt][r][2] * xh[e][r][2] + xd[kt][r][3] * xh[e][r][3];
                    float lg = c[r] * 0.125f + bias4 * 0.5f;
                    lpart[e][r] += __expf(lg);
                }
            }
        }
    }

    // reduce partial sums across the 16 lanes sharing a quad
    float rinv[2][4];
    #pragma unroll
    for (int e = 0; e < 2; ++e)
        #pragma unroll
        for (int r = 0; r < 4; ++r) {
            float s = lpart[e][r];
            s += __shfl_xor(s, 1);
            s += __shfl_xor(s, 2);
            s += __shfl_xor(s, 4);
            s += __shfl_xor(s, 8);
            rinv[e][r] = 1.0f / s;
        }

    // ---- pass 1: recompute, write normalized attn, PV accumulate ----
    f4v oacc[2][4] = {};
    for (int k0 = 0; k0 < S_LEN; k0 += 32) {
        s8v kf[2][2][2];
        #pragma unroll
        for (int e = 0; e < 2; ++e)
            #pragma unroll
            for (int kt = 0; kt < 2; ++kt)
                #pragma unroll
                for (int kk = 0; kk < 2; ++kk)
                    kf[e][kt][kk] = *(const s8v*)&kp[kp_base +
                        (size_t)(k0 + kt * 16 + l15) * 512 + (h0 + e) * 64 + kk * 32 + quad * 8];
        f4v xd[2][4];
        #pragma unroll
        for (int kt = 0; kt < 2; ++kt)
            #pragma unroll
            for (int r = 0; r < 4; ++r)
                xd[kt][r] = *(const f4v*)&xdiff[xd_base +
                    ((size_t)(quad * 4 + r) * S_LEN + k0 + kt * 16 + l15) * 4];

        #pragma unroll
        for (int e = 0; e < 2; ++e) {
            #pragma unroll
            for (int kt = 0; kt < 2; ++kt) {
                f4v c = {0.f, 0.f, 0.f, 0.f};
                c = MFMA16(qf[e][0], kf[e][kt][0], c);
                c = MFMA16(qf[e][1], kf[e][kt][1], c);
                #pragma unroll
                for (int r = 0; r < 4; ++r) {
                    float bias4 = xd[kt][r][0] * xh[e][r][0] + xd[kt][r][1] * xh[e][r][1] +
                                  xd[kt][r][2] * xh[e][r][2] + xd[kt][r][3] * xh[e][r][3];
                    float lg = c[r] * 0.125f + bias4 * 0.5f;
                    float P = __expf(lg) * rinv[e][r];
                    size_t aidx = ((size_t)((b * NH + h0 + e) * S_LEN) + q0 + quad * 4 + r) * S_LEN +
                                  k0 + kt * 16 + l15;
                    __builtin_nontemporal_store(P, &attn[aidx]);
                    p_lds[((w * 2 + e) * 16 + quad * 4 + r) * 32 + kt * 16 + l15] = f2bf(P);
                }
            }
            // P (C-layout) -> A-layout via wave-private LDS; in-wave DS ordering
            s8v pa = *(const s8v*)&p_lds[((w * 2 + e) * 16 + l15) * 32 + quad * 8];
            #pragma unroll
            for (int dt = 0; dt < 4; ++dt) {
                s8v vf = *(const s8v*)&vT[vt_base +
                    (size_t)((h0 + e) * 64 + dt * 16 + l15) * S_LEN + k0 + quad * 8];
                oacc[e][dt] = MFMA16(pa, vf, oacc[e][dt]);
            }
        }
    }

    #pragma unroll
    for (int e = 0; e < 2; ++e)
        #pragma unroll
        for (int dt = 0; dt < 4; ++dt)
            #pragma unroll
            for (int r = 0; r < 4; ++r)
                obuf[((size_t)(b * S_LEN + q0 + quad * 4 + r)) * 512 +
                     (h0 + e) * 64 + dt * 16 + l15] = f2bf(oacc[e][dt][r]);
}

extern "C" void kernel_launch(void* const* d_in, const int* in_sizes, int n_in,
                              void* d_out, int out_size, void* d_ws, size_t ws_size,
                              hipStream_t stream) {
    const float* q     = (const float*)d_in[0];
    const float* k     = (const float*)d_in[1];
    const float* v     = (const float*)d_in[2];
    const float* xdiff = (const float*)d_in[3];
    const float* wq    = (const float*)d_in[4];
    const float* bq    = (const float*)d_in[5];
    const float* wk    = (const float*)d_in[6];
    const float* bk    = (const float*)d_in[7];
    const float* wv    = (const float*)d_in[8];
    const float* bv    = (const float*)d_in[9];
    const float* wx    = (const float*)d_in[10];
    const float* bx    = (const float*)d_in[11];
    const float* wo    = (const float*)d_in[12];
    const float* bo    = (const float*)d_in[13];

    float* outp = (float*)d_out;                       // [4,2048,512] fp32
    float* attn = outp + (size_t)NB * S_LEN * 512;     // [4,8,2048,2048] fp32

    const size_t MK = (size_t)8192 * 512;
    unsigned short* qp   = (unsigned short*)d_ws;      // bf16 [8192][512]
    unsigned short* kpw  = qp + MK;                    // bf16 [8192][512]
    unsigned short* vT   = kpw + MK;                   // bf16 [b][512][2048]
    unsigned short* obuf = vT + MK;                    // bf16 [8192][512]
    float* xws = (float*)(obuf + MK);                  // fp32 [8192][32]

    dim3 gg(128, 8);
    gemm_tile<0, false><<<gg, 256, 0, stream>>>(q, wq, bq, qp);
    gemm_tile<0, false><<<gg, 256, 0, stream>>>(k, wk, bk, kpw);
    gemm_tile<1, false><<<gg, 256, 0, stream>>>(v, wv, bv, vT);
    xproj_kernel<<<1024, 256, 0, stream>>>(qp, wx, bx, xws);
    attn_kernel<<<dim3(128, 4), 256, 0, stream>>>(qp, kpw, vT, xws, xdiff, attn, obuf);
    gemm_tile<2, true><<<gg, 256, 0, stream>>>(obuf, wo, bo, outp);
}